// Round 8
// baseline (167.481 us; speedup 1.0000x reference)
//
#include <hip/hip_runtime.h>
#include <hip/hip_bf16.h>

typedef __attribute__((ext_vector_type(8)))  short short8;   // 8 x bf16
typedef __attribute__((ext_vector_type(4)))  float f32x4;
typedef __attribute__((ext_vector_type(16))) float f32x16;
typedef __attribute__((ext_vector_type(4)))  unsigned int u32x4;

#define LOG2E 1.4426950408889634f

static __device__ __forceinline__ unsigned short f2bf(float f) {
    union { float f; unsigned u; } v; v.f = f;
    unsigned r = v.u + 0x7fffu + ((v.u >> 16) & 1u);   // RNE
    return (unsigned short)(r >> 16);
}
static __device__ __forceinline__ unsigned cvt_pk_bf16(float lo, float hi) {
    unsigned r;
    asm("v_cvt_pk_bf16_f32 %0, %1, %2" : "=v"(r) : "v"(lo), "v"(hi));
    return r;
}
static __device__ __forceinline__ float exp2_hw(float x) {
    float r;
    asm("v_exp_f32 %0, %1" : "=v"(r) : "v"(x));        // D = 2^S0
    return r;
}

// ---------------------------------------------------------------------------
// Kernel 0: W -> fragment-ordered Wtf.  group g = ct*8+kk (ct 0..19, kk 0..7):
// Wtf[g*512 + l*8 + j] = W[kk*32 + (l>>4)*8 + j][ct*16 + (l&15)]
// ---------------------------------------------------------------------------
__global__ __launch_bounds__(64) void transpose_w(
    const float* __restrict__ Wq, const float* __restrict__ Wk,
    const float* __restrict__ Wv, unsigned short* __restrict__ Wtf)
{
    const int g  = blockIdx.x;          // 0..159
    const int ct = g >> 3, kk = g & 7;
    const int l  = threadIdx.x;
    const int col = ct * 16 + (l & 15); // 0..319
    const int k0  = kk * 32 + (l >> 4) * 8;
    const float* W; int c, ldw;
    if (col < 32)      { W = Wq; c = col;      ldw = 32;  }
    else if (col < 64) { W = Wk; c = col - 32; ldw = 32;  }
    else               { W = Wv; c = col - 64; ldw = 256; }
    ushort4 o0, o1;
    o0.x = f2bf(W[(size_t)(k0 + 0) * ldw + c]);
    o0.y = f2bf(W[(size_t)(k0 + 1) * ldw + c]);
    o0.z = f2bf(W[(size_t)(k0 + 2) * ldw + c]);
    o0.w = f2bf(W[(size_t)(k0 + 3) * ldw + c]);
    o1.x = f2bf(W[(size_t)(k0 + 4) * ldw + c]);
    o1.y = f2bf(W[(size_t)(k0 + 5) * ldw + c]);
    o1.z = f2bf(W[(size_t)(k0 + 6) * ldw + c]);
    o1.w = f2bf(W[(size_t)(k0 + 7) * ldw + c]);
    *reinterpret_cast<ushort4*>(Wtf + (size_t)g * 512 + l * 8)     = o0;
    *reinterpret_cast<ushort4*>(Wtf + (size_t)g * 512 + l * 8 + 4) = o1;
}

// ---------------------------------------------------------------------------
// Kernel 1: QKV projection -> fragment-ordered Qb/Kf/Vf (layouts as r5).
// Grid 512 x 256: blockIdx>>1 = 64-token tile, blockIdx&1 = ct half.
// ---------------------------------------------------------------------------
__global__ __launch_bounds__(256) void proj_kernel(
    const float* __restrict__ x, const unsigned short* __restrict__ Wtf,
    const float* __restrict__ bq, const float* __restrict__ bk,
    const float* __restrict__ bv,
    unsigned short* __restrict__ Qb, unsigned short* __restrict__ Kf,
    unsigned short* __restrict__ Vf)
{
    __shared__ unsigned short x_lds[64][264];
    const int tid = threadIdx.x;
    const int M0  = (blockIdx.x >> 1) * 64;
    const int ctb = (blockIdx.x & 1) * 10;

    #pragma unroll
    for (int j = 0; j < 16; ++j) {
        int idx = j * 256 + tid;
        int row = idx >> 6;
        int qc  = idx & 63;
        const float4 v = *reinterpret_cast<const float4*>(x + (size_t)(M0 + row) * 256 + qc * 4);
        ushort4 o;
        o.x = f2bf(v.x); o.y = f2bf(v.y); o.z = f2bf(v.z); o.w = f2bf(v.w);
        *reinterpret_cast<ushort4*>(&x_lds[row][qc * 4]) = o;
    }
    __syncthreads();

    const int w  = tid >> 6;
    const int l  = tid & 63;
    const int lr = l & 15;
    const int lg = l >> 4;

    short8 a[8];
    #pragma unroll
    for (int kk = 0; kk < 8; ++kk)
        a[kk] = *reinterpret_cast<const short8*>(&x_lds[w * 16 + lr][kk * 32 + lg * 8]);

    const int b   = M0 >> 12;          // batch
    const int kt  = (M0 & 4095) >> 6;  // 64-token tile within batch

    for (int ct = ctb; ct < ctb + 10; ++ct) {
        const int col = ct * 16 + lr;           // 0..319
        f32x4 acc = {0.f, 0.f, 0.f, 0.f};
        #pragma unroll
        for (int kk = 0; kk < 8; ++kk) {
            const short8 bfr = *reinterpret_cast<const short8*>(
                Wtf + ((size_t)ct * 8 + kk) * 512 + l * 8);
            acc = __builtin_amdgcn_mfma_f32_16x16x32_bf16(a[kk], bfr, acc, 0, 0, 0);
        }
        const int rbase = M0 + w * 16 + lg * 4;        // global token of reg 0
        if (ct < 2) {           // Q, pre-scaled by log2e
            const float bias = bq[col];
            #pragma unroll
            for (int r = 0; r < 4; ++r)
                Qb[(size_t)(rbase + r) * 32 + col] = f2bf((acc[r] + bias) * LOG2E);
        } else if (ct < 4) {    // K -> fragment layout
            const int colp = col - 32;
            const float bias = bk[colp];
            const int dd = colp >> 4, hj = (colp >> 3) & 1, jj = colp & 7;
            #pragma unroll
            for (int r = 0; r < 4; ++r) {
                const int tt = (rbase + r) & 4095;
                const size_t e = (size_t)b * 131072 + (size_t)kt * 2048
                               + (((tt >> 5) & 1) * 2 + dd) * 512
                               + (hj * 32 + (tt & 31)) * 8 + jj;
                Kf[e] = f2bf(acc[r] + bias);
            }
        } else {                // V -> fragment layout (one 8B write)
            const int colp = col - 64;
            const float bias = bv[colp];
            const int kk_f = w;
            const int hi_v = (lg >> 1) & 1;
            const int j0   = (lg & 1) * 4;
            const size_t e = (size_t)b * 1048576 + (size_t)kt * 16384
                           + (colp >> 5) * 2048 + kk_f * 512
                           + (hi_v * 32 + (colp & 31)) * 8 + j0;
            ushort4 o;
            o.x = f2bf(acc[0] + bias); o.y = f2bf(acc[1] + bias);
            o.z = f2bf(acc[2] + bias); o.w = f2bf(acc[3] + bias);
            *reinterpret_cast<ushort4*>(Vf + e) = o;
        }
    }
}

// ---------------------------------------------------------------------------
// Kernel 2: flash attention, wave = 64q x 64c (2x arithmetic intensity per
// V-byte vs r7: both q-halves reuse each V fragment register).
// Grid 1024 x 128 (2 independent waves, kh K-split). 12KB loads/body/wave.
// ---------------------------------------------------------------------------
__global__ __launch_bounds__(128, 2) void attn_kernel(
    const unsigned short* __restrict__ Qb, const unsigned short* __restrict__ Kf,
    const unsigned short* __restrict__ Vf, const float* __restrict__ x,
    const float* __restrict__ gamma_p, float* __restrict__ out)
{
    __shared__ float O_sh[2][2][16][64];   // [qh][ct] partner partials, 32KB
    __shared__ float l_sh[2][2][32];       // [kh][qh][q]

    const int i  = blockIdx.x;
    const int b  = (i & 7) >> 1;                    // batch -> XCD pair
    const int t  = ((i >> 3) << 1) | (i & 1);       // 0..255
    const int qt = t >> 2;                          // 0..63  (64-row tile)
    const int cg = t & 3;                           // col group of 64

    const int tid = threadIdx.x;
    const int kh  = tid >> 6;                       // K-half wave
    const int l   = tid & 63;
    const int l5  = l & 31;
    const int hi  = l >> 5;

    const size_t bN = (size_t)b * 4096;
    const int q0 = qt * 64;
    const int c0 = cg * 64;

    const unsigned short* Kfb = Kf + (size_t)b * 131072 + l * 8;
    const unsigned short* Vfb = Vf + (size_t)b * 1048576 + (size_t)cg * 4096 + l * 8;

    // Q B-frags for both q-halves (pre-scaled by log2e in proj)
    short8 qb[2][2];
    #pragma unroll
    for (int qh = 0; qh < 2; ++qh)
        #pragma unroll
        for (int dd = 0; dd < 2; ++dd)
            qb[qh][dd] = *reinterpret_cast<const short8*>(
                Qb + (bN + (size_t)(q0 + qh * 32 + l5)) * 32 + dd * 16 + hi * 8);

    f32x16 Oa[2][2];                                // [qh][ct]
    #pragma unroll
    for (int qh = 0; qh < 2; ++qh)
        #pragma unroll
        for (int ct = 0; ct < 2; ++ct)
            #pragma unroll
            for (int r = 0; r < 16; ++r) Oa[qh][ct][r] = 0.f;
    float lsA[2] = {0.f, 0.f}, lsB[2] = {0.f, 0.f}; // rowsum dual accumulators

    f32x16 z;
    #pragma unroll
    for (int r = 0; r < 16; ++r) z[r] = 0.f;

    const int kt0 = kh * 32;                        // wave's first 64-token tile

    auto loadK = [&](short8 (&kA)[2][2], int ktg) {
        const unsigned short* kp = Kfb + (size_t)ktg * 2048;
        #pragma unroll
        for (int ks = 0; ks < 2; ++ks)
            #pragma unroll
            for (int dd = 0; dd < 2; ++dd)
                kA[ks][dd] = *reinterpret_cast<const short8*>(kp + (ks * 2 + dd) * 512);
    };

    short8 pa[2][4];                                // [qh][k-frag]
    auto build_pa = [&](int qh, const f32x16& p, int base) {
        unsigned c[8];
        #pragma unroll
        for (int n = 0; n < 8; ++n) {
            const float e0 = exp2_hw(p[2 * n]);
            const float e1 = exp2_hw(p[2 * n + 1]);
            lsA[qh] += e0; lsB[qh] += e1;
            c[n] = cvt_pk_bf16(e0, e1);
        }
        #pragma unroll
        for (int k2 = 0; k2 < 2; ++k2) {
            unsigned d0 = c[4 * k2 + 0], d2 = c[4 * k2 + 2];
            unsigned d1 = c[4 * k2 + 1], d3 = c[4 * k2 + 3];
            asm("v_permlane32_swap_b32 %0, %1" : "+v"(d0), "+v"(d2));
            asm("v_permlane32_swap_b32 %0, %1" : "+v"(d1), "+v"(d3));
            u32x4 u = {d0, d1, d2, d3};
            pa[qh][base + k2] = __builtin_bit_cast(short8, u);
        }
    };

    auto body = [&](short8 (&kcur)[2][2], short8 (&knxt)[2][2], int ktg, int ktgn) {
        const unsigned short* vp = Vfb + (size_t)ktg * 16384;
        // ALL 8 V fragments (64k x 64c) upfront -> covered by QK+softmax
        short8 vf[2][4];
        #pragma unroll
        for (int ct = 0; ct < 2; ++ct)
            #pragma unroll
            for (int kk = 0; kk < 4; ++kk)
                vf[ct][kk] = *reinterpret_cast<const short8*>(vp + ct * 2048 + kk * 512);
        loadK(knxt, ktgn);                          // next K tile in flight
        // swapped QK^T per (qh, ks); sequential p caps register pressure
        #pragma unroll
        for (int qh = 0; qh < 2; ++qh)
            #pragma unroll
            for (int ks = 0; ks < 2; ++ks) {
                f32x16 p = __builtin_amdgcn_mfma_f32_32x32x16_bf16(kcur[ks][0], qb[qh][0], z, 0, 0, 0);
                p        = __builtin_amdgcn_mfma_f32_32x32x16_bf16(kcur[ks][1], qb[qh][1], p, 0, 0, 0);
                build_pa(qh, p, ks * 2);
            }
        // PV: both q-halves consume the same vf registers (the intensity win)
        __builtin_amdgcn_s_setprio(1);
        #pragma unroll
        for (int ct = 0; ct < 2; ++ct)
            #pragma unroll
            for (int qh = 0; qh < 2; ++qh)
                #pragma unroll
                for (int kk = 0; kk < 4; ++kk)
                    Oa[qh][ct] = __builtin_amdgcn_mfma_f32_32x32x16_bf16(
                        pa[qh][kk], vf[ct][kk], Oa[qh][ct], 0, 0, 0);
        __builtin_amdgcn_s_setprio(0);
    };

    short8 kA0[2][2], kA1[2][2];
    loadK(kA0, kt0);
    for (int kt = 0; kt < 32; kt += 2) {
        body(kA0, kA1, kt0 + kt, kt0 + kt + 1);
        body(kA1, kA0, kt0 + kt + 1, kt0 + ((kt + 2) & 31));   // last prefetch wraps
    }

    // ---- publish rowsums ----
    #pragma unroll
    for (int qh = 0; qh < 2; ++qh) {
        float s = lsA[qh] + lsB[qh];
        s += __shfl_xor(s, 32);
        if (hi == 0) l_sh[kh][qh][l5] = s;
    }
    // ---- partner O partials via LDS (wave kh finalizes qh==kh) ----
    #pragma unroll
    for (int qh = 0; qh < 2; ++qh)
        if (qh != kh) {
            #pragma unroll
            for (int ct = 0; ct < 2; ++ct)
                #pragma unroll
                for (int r = 0; r < 16; ++r)
                    O_sh[qh][ct][r][hi * 32 + l5] = Oa[qh][ct][r];
        }
    __syncthreads();

    const float gamma = gamma_p[0];
    {
        const int qh = kh;
        #pragma unroll
        for (int ct = 0; ct < 2; ++ct)
            #pragma unroll
            for (int r = 0; r < 16; ++r) {
                const int qr = (r & 3) + 8 * (r >> 2) + 4 * hi;
                const float ltot = l_sh[0][qh][qr] + l_sh[1][qh][qr];
                const float osum = Oa[qh][ct][r] + O_sh[qh][ct][r][hi * 32 + l5];
                const size_t idx = (bN + (size_t)(q0 + qh * 32 + qr)) * 256 + c0 + ct * 32 + l5;
                out[idx] = gamma * (osum / ltot) + x[idx];
            }
    }
}

// ---------------------------------------------------------------------------
extern "C" void kernel_launch(void* const* d_in, const int* in_sizes, int n_in,
                              void* d_out, int out_size, void* d_ws, size_t ws_size,
                              hipStream_t stream) {
    const float* x     = (const float*)d_in[0];
    const float* Wq    = (const float*)d_in[1];
    const float* bq    = (const float*)d_in[2];
    const float* Wk    = (const float*)d_in[3];
    const float* bk    = (const float*)d_in[4];
    const float* Wv    = (const float*)d_in[5];
    const float* bv    = (const float*)d_in[6];
    const float* gamma = (const float*)d_in[7];
    float* out = (float*)d_out;

    // workspace: Qb 1MB | Kf 1MB | Vf 8MB | Wtf 160KB (bf16)
    unsigned short* Qb  = (unsigned short*)d_ws;
    unsigned short* Kf  = Qb + (size_t)16384 * 32;
    unsigned short* Vf  = Kf + (size_t)16384 * 32;
    unsigned short* Wtf = Vf + (size_t)4 * 256 * 4096;

    transpose_w<<<160, 64, 0, stream>>>(Wq, Wk, Wv, Wtf);
    proj_kernel<<<512, 256, 0, stream>>>(x, Wtf, bq, bk, bv, Qb, Kf, Vf);
    attn_kernel<<<1024, 128, 0, stream>>>(Qb, Kf, Vf, x, gamma, out);
}

// Round 9
// 92.660 us; speedup vs baseline: 1.8075x; 1.8075x over previous
//
#include <hip/hip_runtime.h>
#include <hip/hip_bf16.h>

typedef __attribute__((ext_vector_type(8)))  short short8;   // 8 x bf16
typedef __attribute__((ext_vector_type(4)))  float f32x4;
typedef __attribute__((ext_vector_type(16))) float f32x16;
typedef __attribute__((ext_vector_type(4)))  unsigned int u32x4;

#define LOG2E 1.4426950408889634f

static __device__ __forceinline__ unsigned short f2bf(float f) {
    union { float f; unsigned u; } v; v.f = f;
    unsigned r = v.u + 0x7fffu + ((v.u >> 16) & 1u);   // RNE
    return (unsigned short)(r >> 16);
}
static __device__ __forceinline__ unsigned cvt_pk_bf16(float lo, float hi) {
    unsigned r;
    asm("v_cvt_pk_bf16_f32 %0, %1, %2" : "=v"(r) : "v"(lo), "v"(hi));
    return r;
}
static __device__ __forceinline__ float exp2_hw(float x) {
    float r;
    asm("v_exp_f32 %0, %1" : "=v"(r) : "v"(x));        // D = 2^S0
    return r;
}

// ---------------------------------------------------------------------------
// Kernel 0: W -> fragment-ordered Wtf.  group g = ct*8+kk (ct 0..19, kk 0..7):
// Wtf[g*512 + l*8 + j] = W[kk*32 + (l>>4)*8 + j][ct*16 + (l&15)]
// ---------------------------------------------------------------------------
__global__ __launch_bounds__(64) void transpose_w(
    const float* __restrict__ Wq, const float* __restrict__ Wk,
    const float* __restrict__ Wv, unsigned short* __restrict__ Wtf)
{
    const int g  = blockIdx.x;          // 0..159
    const int ct = g >> 3, kk = g & 7;
    const int l  = threadIdx.x;
    const int col = ct * 16 + (l & 15); // 0..319
    const int k0  = kk * 32 + (l >> 4) * 8;
    const float* W; int c, ldw;
    if (col < 32)      { W = Wq; c = col;      ldw = 32;  }
    else if (col < 64) { W = Wk; c = col - 32; ldw = 32;  }
    else               { W = Wv; c = col - 64; ldw = 256; }
    ushort4 o0, o1;
    o0.x = f2bf(W[(size_t)(k0 + 0) * ldw + c]);
    o0.y = f2bf(W[(size_t)(k0 + 1) * ldw + c]);
    o0.z = f2bf(W[(size_t)(k0 + 2) * ldw + c]);
    o0.w = f2bf(W[(size_t)(k0 + 3) * ldw + c]);
    o1.x = f2bf(W[(size_t)(k0 + 4) * ldw + c]);
    o1.y = f2bf(W[(size_t)(k0 + 5) * ldw + c]);
    o1.z = f2bf(W[(size_t)(k0 + 6) * ldw + c]);
    o1.w = f2bf(W[(size_t)(k0 + 7) * ldw + c]);
    *reinterpret_cast<ushort4*>(Wtf + (size_t)g * 512 + l * 8)     = o0;
    *reinterpret_cast<ushort4*>(Wtf + (size_t)g * 512 + l * 8 + 4) = o1;
}

// ---------------------------------------------------------------------------
// Kernel 1: QKV projection -> fragment-ordered Qb/Kf/Vf (layouts as r5).
// Grid 512 x 256: blockIdx>>1 = 64-token tile, blockIdx&1 = ct half.
// ---------------------------------------------------------------------------
__global__ __launch_bounds__(256) void proj_kernel(
    const float* __restrict__ x, const unsigned short* __restrict__ Wtf,
    const float* __restrict__ bq, const float* __restrict__ bk,
    const float* __restrict__ bv,
    unsigned short* __restrict__ Qb, unsigned short* __restrict__ Kf,
    unsigned short* __restrict__ Vf)
{
    __shared__ unsigned short x_lds[64][264];
    const int tid = threadIdx.x;
    const int M0  = (blockIdx.x >> 1) * 64;
    const int ctb = (blockIdx.x & 1) * 10;

    #pragma unroll
    for (int j = 0; j < 16; ++j) {
        int idx = j * 256 + tid;
        int row = idx >> 6;
        int qc  = idx & 63;
        const float4 v = *reinterpret_cast<const float4*>(x + (size_t)(M0 + row) * 256 + qc * 4);
        ushort4 o;
        o.x = f2bf(v.x); o.y = f2bf(v.y); o.z = f2bf(v.z); o.w = f2bf(v.w);
        *reinterpret_cast<ushort4*>(&x_lds[row][qc * 4]) = o;
    }
    __syncthreads();

    const int w  = tid >> 6;
    const int l  = tid & 63;
    const int lr = l & 15;
    const int lg = l >> 4;

    short8 a[8];
    #pragma unroll
    for (int kk = 0; kk < 8; ++kk)
        a[kk] = *reinterpret_cast<const short8*>(&x_lds[w * 16 + lr][kk * 32 + lg * 8]);

    const int b   = M0 >> 12;          // batch
    const int kt  = (M0 & 4095) >> 6;  // 64-token tile within batch

    for (int ct = ctb; ct < ctb + 10; ++ct) {
        const int col = ct * 16 + lr;           // 0..319
        f32x4 acc = {0.f, 0.f, 0.f, 0.f};
        #pragma unroll
        for (int kk = 0; kk < 8; ++kk) {
            const short8 bfr = *reinterpret_cast<const short8*>(
                Wtf + ((size_t)ct * 8 + kk) * 512 + l * 8);
            acc = __builtin_amdgcn_mfma_f32_16x16x32_bf16(a[kk], bfr, acc, 0, 0, 0);
        }
        const int rbase = M0 + w * 16 + lg * 4;        // global token of reg 0
        if (ct < 2) {           // Q, pre-scaled by log2e
            const float bias = bq[col];
            #pragma unroll
            for (int r = 0; r < 4; ++r)
                Qb[(size_t)(rbase + r) * 32 + col] = f2bf((acc[r] + bias) * LOG2E);
        } else if (ct < 4) {    // K -> fragment layout
            const int colp = col - 32;
            const float bias = bk[colp];
            const int dd = colp >> 4, hj = (colp >> 3) & 1, jj = colp & 7;
            #pragma unroll
            for (int r = 0; r < 4; ++r) {
                const int tt = (rbase + r) & 4095;
                const size_t e = (size_t)b * 131072 + (size_t)kt * 2048
                               + (((tt >> 5) & 1) * 2 + dd) * 512
                               + (hj * 32 + (tt & 31)) * 8 + jj;
                Kf[e] = f2bf(acc[r] + bias);
            }
        } else {                // V -> fragment layout (one 8B write)
            const int colp = col - 64;
            const float bias = bv[colp];
            const int kk_f = w;
            const int hi_v = (lg >> 1) & 1;
            const int j0   = (lg & 1) * 4;
            const size_t e = (size_t)b * 1048576 + (size_t)kt * 16384
                           + (colp >> 5) * 2048 + kk_f * 512
                           + (hi_v * 32 + (colp & 31)) * 8 + j0;
            ushort4 o;
            o.x = f2bf(acc[0] + bias); o.y = f2bf(acc[1] + bias);
            o.z = f2bf(acc[2] + bias); o.w = f2bf(acc[3] + bias);
            *reinterpret_cast<ushort4*>(Vf + e) = o;
        }
    }
}

// ---------------------------------------------------------------------------
// Kernel 2: flash attention, wave = 64q x 64c, register-dieted (~190 regs):
// sequential qh with shared pa[4], single-buffer kA reloaded after last use.
// Grid 1024 x 128 (2 independent waves, kh K-split). 12KB loads/body/wave.
// ---------------------------------------------------------------------------
__global__ __launch_bounds__(128, 2) void attn_kernel(
    const unsigned short* __restrict__ Qb, const unsigned short* __restrict__ Kf,
    const unsigned short* __restrict__ Vf, const float* __restrict__ x,
    const float* __restrict__ gamma_p, float* __restrict__ out)
{
    __shared__ float O_sh[2][2][16][64];   // [qh][ct] partner partials, 32KB
    __shared__ float l_sh[2][2][32];       // [kh][qh][q]

    const int i  = blockIdx.x;
    const int b  = (i & 7) >> 1;                    // batch -> XCD pair
    const int t  = ((i >> 3) << 1) | (i & 1);       // 0..255
    const int qt = t >> 2;                          // 0..63  (64-row tile)
    const int cg = t & 3;                           // col group of 64

    const int tid = threadIdx.x;
    const int kh  = tid >> 6;                       // K-half wave
    const int l   = tid & 63;
    const int l5  = l & 31;
    const int hi  = l >> 5;

    const size_t bN = (size_t)b * 4096;
    const int q0 = qt * 64;
    const int c0 = cg * 64;

    const unsigned short* Kfb = Kf + (size_t)b * 131072 + l * 8;
    const unsigned short* Vfb = Vf + (size_t)b * 1048576 + (size_t)cg * 4096 + l * 8;

    // Q B-frags for both q-halves (pre-scaled by log2e in proj)
    short8 qb[2][2];
    #pragma unroll
    for (int qh = 0; qh < 2; ++qh)
        #pragma unroll
        for (int dd = 0; dd < 2; ++dd)
            qb[qh][dd] = *reinterpret_cast<const short8*>(
                Qb + (bN + (size_t)(q0 + qh * 32 + l5)) * 32 + dd * 16 + hi * 8);

    f32x16 Oa[2][2];                                // [qh][ct]
    #pragma unroll
    for (int qh = 0; qh < 2; ++qh)
        #pragma unroll
        for (int ct = 0; ct < 2; ++ct)
            #pragma unroll
            for (int r = 0; r < 16; ++r) Oa[qh][ct][r] = 0.f;
    float lsA[2] = {0.f, 0.f}, lsB[2] = {0.f, 0.f}; // rowsum dual accumulators

    f32x16 z;
    #pragma unroll
    for (int r = 0; r < 16; ++r) z[r] = 0.f;

    const int kt0 = kh * 32;                        // wave's first 64-token tile

    short8 kA[2][2];                                // single K buffer
    auto loadK = [&](int ktg) {
        const unsigned short* kp = Kfb + (size_t)ktg * 2048;
        #pragma unroll
        for (int ks = 0; ks < 2; ++ks)
            #pragma unroll
            for (int dd = 0; dd < 2; ++dd)
                kA[ks][dd] = *reinterpret_cast<const short8*>(kp + (ks * 2 + dd) * 512);
    };

    short8 pa[4];                                   // shared across qh
    auto build_pa = [&](int qh, const f32x16& p, int base) {
        unsigned c[8];
        #pragma unroll
        for (int n = 0; n < 8; ++n) {
            const float e0 = exp2_hw(p[2 * n]);
            const float e1 = exp2_hw(p[2 * n + 1]);
            lsA[qh] += e0; lsB[qh] += e1;
            c[n] = cvt_pk_bf16(e0, e1);
        }
        #pragma unroll
        for (int k2 = 0; k2 < 2; ++k2) {
            unsigned d0 = c[4 * k2 + 0], d2 = c[4 * k2 + 2];
            unsigned d1 = c[4 * k2 + 1], d3 = c[4 * k2 + 3];
            asm("v_permlane32_swap_b32 %0, %1" : "+v"(d0), "+v"(d2));
            asm("v_permlane32_swap_b32 %0, %1" : "+v"(d1), "+v"(d3));
            u32x4 u = {d0, d1, d2, d3};
            pa[base + k2] = __builtin_bit_cast(short8, u);
        }
    };

    auto body = [&](int ktg, int ktgn) {
        const unsigned short* vp = Vfb + (size_t)ktg * 16384;
        // ALL 8 V fragments (64k x 64c) upfront -> covered by QK+softmax
        short8 vf[2][4];
        #pragma unroll
        for (int ct = 0; ct < 2; ++ct)
            #pragma unroll
            for (int kk = 0; kk < 4; ++kk)
                vf[ct][kk] = *reinterpret_cast<const short8*>(vp + ct * 2048 + kk * 512);

        // ---- qh = 0: QK -> softmax -> PV (vf stays live) ----
        {
            f32x16 p = __builtin_amdgcn_mfma_f32_32x32x16_bf16(kA[0][0], qb[0][0], z, 0, 0, 0);
            p        = __builtin_amdgcn_mfma_f32_32x32x16_bf16(kA[0][1], qb[0][1], p, 0, 0, 0);
            build_pa(0, p, 0);
        }
        {
            f32x16 p = __builtin_amdgcn_mfma_f32_32x32x16_bf16(kA[1][0], qb[0][0], z, 0, 0, 0);
            p        = __builtin_amdgcn_mfma_f32_32x32x16_bf16(kA[1][1], qb[0][1], p, 0, 0, 0);
            build_pa(0, p, 2);
        }
        __builtin_amdgcn_s_setprio(1);
        #pragma unroll
        for (int ct = 0; ct < 2; ++ct)
            #pragma unroll
            for (int kk = 0; kk < 4; ++kk)
                Oa[0][ct] = __builtin_amdgcn_mfma_f32_32x32x16_bf16(
                    pa[kk], vf[ct][kk], Oa[0][ct], 0, 0, 0);
        __builtin_amdgcn_s_setprio(0);

        // ---- qh = 1: QK (last kA use) -> reload kA -> softmax -> PV ----
        f32x16 p0 = __builtin_amdgcn_mfma_f32_32x32x16_bf16(kA[0][0], qb[1][0], z, 0, 0, 0);
        p0        = __builtin_amdgcn_mfma_f32_32x32x16_bf16(kA[0][1], qb[1][1], p0, 0, 0, 0);
        f32x16 p1 = __builtin_amdgcn_mfma_f32_32x32x16_bf16(kA[1][0], qb[1][0], z, 0, 0, 0);
        p1        = __builtin_amdgcn_mfma_f32_32x32x16_bf16(kA[1][1], qb[1][1], p1, 0, 0, 0);
        loadK(ktgn);                               // next-body K, covered by below
        build_pa(1, p0, 0);
        build_pa(1, p1, 2);
        __builtin_amdgcn_s_setprio(1);
        #pragma unroll
        for (int ct = 0; ct < 2; ++ct)
            #pragma unroll
            for (int kk = 0; kk < 4; ++kk)
                Oa[1][ct] = __builtin_amdgcn_mfma_f32_32x32x16_bf16(
                    pa[kk], vf[ct][kk], Oa[1][ct], 0, 0, 0);
        __builtin_amdgcn_s_setprio(0);
    };

    loadK(kt0);
    for (int kt = 0; kt < 32; ++kt)
        body(kt0 + kt, kt0 + ((kt + 1) & 31));      // last prefetch wraps harmlessly

    // ---- publish rowsums ----
    #pragma unroll
    for (int qh = 0; qh < 2; ++qh) {
        float s = lsA[qh] + lsB[qh];
        s += __shfl_xor(s, 32);
        if (hi == 0) l_sh[kh][qh][l5] = s;
    }
    // ---- partner O partials via LDS (wave kh finalizes qh==kh) ----
    #pragma unroll
    for (int qh = 0; qh < 2; ++qh)
        if (qh != kh) {
            #pragma unroll
            for (int ct = 0; ct < 2; ++ct)
                #pragma unroll
                for (int r = 0; r < 16; ++r)
                    O_sh[qh][ct][r][hi * 32 + l5] = Oa[qh][ct][r];
        }
    __syncthreads();

    const float gamma = gamma_p[0];
    {
        const int qh = kh;
        #pragma unroll
        for (int ct = 0; ct < 2; ++ct)
            #pragma unroll
            for (int r = 0; r < 16; ++r) {
                const int qr = (r & 3) + 8 * (r >> 2) + 4 * hi;
                const float ltot = l_sh[0][qh][qr] + l_sh[1][qh][qr];
                const float osum = Oa[qh][ct][r] + O_sh[qh][ct][r][hi * 32 + l5];
                const size_t idx = (bN + (size_t)(q0 + qh * 32 + qr)) * 256 + c0 + ct * 32 + l5;
                out[idx] = gamma * (osum / ltot) + x[idx];
            }
    }
}

// ---------------------------------------------------------------------------
extern "C" void kernel_launch(void* const* d_in, const int* in_sizes, int n_in,
                              void* d_out, int out_size, void* d_ws, size_t ws_size,
                              hipStream_t stream) {
    const float* x     = (const float*)d_in[0];
    const float* Wq    = (const float*)d_in[1];
    const float* bq    = (const float*)d_in[2];
    const float* Wk    = (const float*)d_in[3];
    const float* bk    = (const float*)d_in[4];
    const float* Wv    = (const float*)d_in[5];
    const float* bv    = (const float*)d_in[6];
    const float* gamma = (const float*)d_in[7];
    float* out = (float*)d_out;

    // workspace: Qb 1MB | Kf 1MB | Vf 8MB | Wtf 160KB (bf16)
    unsigned short* Qb  = (unsigned short*)d_ws;
    unsigned short* Kf  = Qb + (size_t)16384 * 32;
    unsigned short* Vf  = Kf + (size_t)16384 * 32;
    unsigned short* Wtf = Vf + (size_t)4 * 256 * 4096;

    transpose_w<<<160, 64, 0, stream>>>(Wq, Wk, Wv, Wtf);
    proj_kernel<<<512, 256, 0, stream>>>(x, Wtf, bq, bk, bv, Qb, Kf, Vf);
    attn_kernel<<<1024, 128, 0, stream>>>(Qb, Kf, Vf, x, gamma, out);
}